// Round 13
// baseline (136.099 us; speedup 1.0000x reference)
//
#include <hip/hip_runtime.h>

// VQEmbedding: B=32,T=1024,D=256,K=1024. N=32768 rows.
// Exact score (proven r2-r11): s = fl32( fl32(csqr_k + xsqr_i) - 2*dot_ik ), argmin,
// first-index ties via packed u64 keys. bf16 MFMA approx (fragment layout verified
// r4-r11); SINGLE-PASS running-threshold candidate filter; exact fp32 rescore (r2 chain).
// r12 design constraints (measured r9-r11): barrier-free main loop (r9/r10: ~70% dead
// time from barrier-per-chunk); live set <= 128 VGPR (r11: compiler caps at 128, spill
// = +32MB phantom WRITE); full reg double-buffer for B (r5: MLP matters).
// Single-pass soundness: append code k iff s(k) <= runm_after(k) + M. Winner: runm_after
// <= s(k*) -> always appended. Exact ties: s(k) <= min_global + 2eps <= runm_visit + M
// (M=1.5e-3 > 2eps~7e-4, r6-proven). Overflow -> exact brute-force fallback.
// (r12 bench was an infra failure — same wedged container as r7/r8, transport error
//  before push; kernel never ran. Resubmitted unchanged.)

#define NROWS  32768
#define DDIM   256
#define KCODES 1024
#define MARGIN 1.5e-3f
#define CAP    2048
#define RPB    64          // rows per block (4 waves x 16 rows)

typedef __attribute__((ext_vector_type(8))) short short8;
typedef __attribute__((ext_vector_type(4))) float f32x4;

__device__ __forceinline__ unsigned short f2bf(float f) {   // RNE f32->bf16
    unsigned u = __float_as_uint(f);
    return (unsigned short)((u + 0x7FFFu + ((u >> 16) & 1u)) >> 16);
}

// exact fp32 dot — BIT-IDENTICAL chain to r2-r11 (proven). DO NOT reorder.
__device__ __forceinline__ float exact_dot(const float* __restrict__ xrow,
                                           const float* __restrict__ crow) {
    const float4* xp = (const float4*)xrow;
    const float4* cp = (const float4*)crow;
    float A = 0.f, B = 0.f;
    #pragma unroll 8
    for (int d4 = 0; d4 < 32; ++d4) {
        float4 xv = xp[d4], cv = cp[d4];
        A = __fmaf_rn(xv.x, cv.x, A);
        A = __fmaf_rn(xv.y, cv.y, A);
        A = __fmaf_rn(xv.z, cv.z, A);
        A = __fmaf_rn(xv.w, cv.w, A);
    }
    #pragma unroll 8
    for (int d4 = 32; d4 < 64; ++d4) {
        float4 xv = xp[d4], cv = cp[d4];
        B = __fmaf_rn(xv.x, cv.x, B);
        B = __fmaf_rn(xv.y, cv.y, B);
        B = __fmaf_rn(xv.z, cv.z, B);
        B = __fmaf_rn(xv.w, cv.w, B);
    }
    return __fadd_rn(A, B);
}

// --- csqr[k] (proven r2-r11, unchanged) ---
__global__ __launch_bounds__(256) void vq_csqr(const float* __restrict__ cb,
                                               float* __restrict__ csqr) {
    int gid  = blockIdx.x * 256 + threadIdx.x;
    int w    = gid >> 6;
    int lane = threadIdx.x & 63;
    if (w >= KCODES) return;
    float4 v = reinterpret_cast<const float4*>(cb)[w * (DDIM / 4) + lane];
    float s = v.x * v.x + v.y * v.y + v.z * v.z + v.w * v.w;
    #pragma unroll
    for (int off = 32; off > 0; off >>= 1) s += __shfl_down(s, off, 64);
    if (lane == 0) csqr[w] = s;
}

// --- xsqr[r] (proven r3-r11, unchanged) ---
__global__ __launch_bounds__(256) void vq_xsqr(const float* __restrict__ x,
                                               float* __restrict__ xsqr) {
    int w = threadIdx.x >> 6, lane = threadIdx.x & 63;
    int row = blockIdx.x * 4 + w;
    float4 v = reinterpret_cast<const float4*>(x + (size_t)row * DDIM)[lane];
    float s = v.x * v.x + v.y * v.y + v.z * v.z + v.w * v.w;
    #pragma unroll
    for (int off = 32; off > 0; off >>= 1) s += __shfl_down(s, off, 64);
    if (lane == 0) xsqr[row] = s;
}

// --- cb -> bf16 B-fragments (layout verified r4-r11): frag(nt,ks): lane l elem i =
//     cb[nt*16 + (l&15)][ks*32 + (l>>4)*8 + i]; linear id = (nt*8+ks)*64 + l ---
__global__ __launch_bounds__(256) void vq_cbfrag(const float* __restrict__ cb,
                                                 short* __restrict__ cbh) {
    int id   = blockIdx.x * 256 + threadIdx.x;
    int lane = id & 63;
    int ks   = (id >> 6) & 7;
    int nt   = id >> 9;
    int code = nt * 16 + (lane & 15);
    int d0   = ks * 32 + (lane >> 4) * 8;
    const float4* p = (const float4*)(cb + (size_t)code * DDIM + d0);
    float4 a = p[0], b = p[1];
    short8 v;
    v[0] = (short)f2bf(a.x); v[1] = (short)f2bf(a.y);
    v[2] = (short)f2bf(a.z); v[3] = (short)f2bf(a.w);
    v[4] = (short)f2bf(b.x); v[5] = (short)f2bf(b.y);
    v[6] = (short)f2bf(b.z); v[7] = (short)f2bf(b.w);
    *(short8*)(cbh + (size_t)id * 8) = v;
}

// --- main: 64 rows/block, 4 waves x 16 rows; each wave scans ALL 64 nt once;
//     barrier-free loop, B double-buffered in registers from L2. ---
__global__ __launch_bounds__(256, 4) void vq_main(const float* __restrict__ x,
                                                  const float* __restrict__ cb,
                                                  const short* __restrict__ cbh,
                                                  const float* __restrict__ csqr,
                                                  const float* __restrict__ xsqr,
                                                  float* __restrict__ out) {
    __shared__ float              csl[KCODES];   // 4KB
    __shared__ unsigned long long keys[RPB];
    __shared__ unsigned           list[CAP];     // 8KB
    __shared__ int                fidx[RPB];
    __shared__ int                cnt, ovf;

    const int t    = threadIdx.x;
    const int lane = t & 63;
    const int w    = t >> 6;         // 0..3 (wave = 16-row tile)
    const int r0   = blockIdx.x * RPB;
    const int lr   = lane & 15;
    const int lg   = lane >> 4;

    ((float4*)csl)[t] = ((const float4*)csqr)[t];
    if (t < RPB) keys[t] = ~0ULL;
    if (t == 0) { cnt = 0; ovf = 0; }
    __syncthreads();                 // init visible (only pre-loop barrier)

    // A-fragments for this wave's 16 rows (mapping identical to r4-r11).
    short8 afr[8];
    {
        const float* xr = x + (size_t)(r0 + w * 16 + lr) * DDIM;
        #pragma unroll
        for (int ks = 0; ks < 8; ++ks) {
            float4 a = *(const float4*)&xr[ks * 32 + lg * 8];
            float4 b = *(const float4*)&xr[ks * 32 + lg * 8 + 4];
            short8 v;
            v[0] = (short)f2bf(a.x); v[1] = (short)f2bf(a.y);
            v[2] = (short)f2bf(a.z); v[3] = (short)f2bf(a.w);
            v[4] = (short)f2bf(b.x); v[5] = (short)f2bf(b.y);
            v[6] = (short)f2bf(b.z); v[7] = (short)f2bf(b.w);
            afr[ks] = v;
        }
    }

    const short8* cbh8 = (const short8*)cbh;
    auto load_bv = [&](short8 (&bv)[8], int nt) {
        const short8* bp = cbh8 + (size_t)(nt * 8) * 64 + lane;
        #pragma unroll
        for (int ks = 0; ks < 8; ++ks) bv[ks] = bp[(size_t)ks * 64];
    };

    float runm[4] = {__builtin_inff(), __builtin_inff(), __builtin_inff(), __builtin_inff()};

    // single pass over all 64 code-tiles: score -> row-min butterfly -> running
    // threshold append. No barriers; appends via LDS atomics.
    auto tile_step = [&](const short8 (&bv)[8], int nt) {
        f32x4 af = (f32x4){0.f, 0.f, 0.f, 0.f};
        #pragma unroll
        for (int ks = 0; ks < 8; ++ks)
            af = __builtin_amdgcn_mfma_f32_16x16x32_bf16(afr[ks], bv[ks], af, 0, 0, 0);
        const int code = nt * 16 + lr;
        const float cs1 = __fadd_rn(csl[code], 1.0f);   // +1 shift (uniform, proven form)
        float s[4];
        #pragma unroll
        for (int j = 0; j < 4; ++j) {
            s[j] = __fmaf_rn(-2.f, af[j], cs1);
            float v = s[j];
            v = fminf(v, __shfl_xor(v, 1, 64));
            v = fminf(v, __shfl_xor(v, 2, 64));
            v = fminf(v, __shfl_xor(v, 4, 64));
            v = fminf(v, __shfl_xor(v, 8, 64));   // row-min of this tile
            runm[j] = fminf(runm[j], v);
            if (s[j] <= runm[j] + MARGIN) {
                int row = w * 16 + lg * 4 + j;
                int pos = atomicAdd(&cnt, 1);
                if (pos < CAP) list[pos] = ((unsigned)row << 10) | (unsigned)code;
                else ovf = 1;
            }
        }
    };

    short8 bvA[8], bvB[8];
    load_bv(bvA, 0);
    for (int c = 0; c < 64; c += 2) {
        load_bv(bvB, c + 1);
        tile_step(bvA, c);
        if (c + 2 < 64) load_bv(bvA, c + 2);
        tile_step(bvB, c + 1);
    }
    __syncthreads();   // all candidates in list

    // ---- exact rescore (r2-proven chain + grid formula), u64 first-index argmin ----
    if (ovf || cnt > CAP) {
        for (int it = t; it < RPB * KCODES; it += 256) {   // safety net (never fires)
            int row = it >> 10, code = it & (KCODES - 1);
            float dot = exact_dot(x + (size_t)(r0 + row) * DDIM, cb + (size_t)code * DDIM);
            float s   = __fmaf_rn(-2.f, dot, __fadd_rn(csl[code], xsqr[r0 + row]));
            atomicMin(&keys[row], ((unsigned long long)__float_as_uint(s) << 32) | (unsigned)code);
        }
    } else {
        for (int i = t; i < cnt; i += 256) {
            unsigned e = list[i];
            int row = (int)(e >> 10), code = (int)(e & 0x3FFu);
            float dot = exact_dot(x + (size_t)(r0 + row) * DDIM, cb + (size_t)code * DDIM);
            float s   = __fmaf_rn(-2.f, dot, __fadd_rn(csl[code], xsqr[r0 + row]));
            atomicMin(&keys[row], ((unsigned long long)__float_as_uint(s) << 32) | (unsigned)code);
        }
    }
    __syncthreads();

    if (t < RPB) {
        int code = (int)(unsigned)(keys[t] & 0xffffffffu);
        fidx[t] = code;
        out[(size_t)2 * NROWS * DDIM + (r0 + t)] = (float)code;
    }
    __syncthreads();

    // gather winning codes: 64 rows x 64 float4, coalesced
    const float4* cb4  = (const float4*)cb;
    float4*       out0 = (float4*)out;
    float4*       out1 = out0 + (size_t)NROWS * (DDIM / 4);
    #pragma unroll
    for (int i = 0; i < 16; ++i) {
        int it  = i * 256 + t;
        int row = it >> 6, col = it & 63;
        float4 v = cb4[(size_t)fidx[row] * (DDIM / 4) + col];
        size_t o = (size_t)(r0 + row) * (DDIM / 4) + col;
        out0[o] = v;
        out1[o] = v;
    }
}

extern "C" void kernel_launch(void* const* d_in, const int* in_sizes, int n_in,
                              void* d_out, int out_size, void* d_ws, size_t ws_size,
                              hipStream_t stream) {
    const float* x   = (const float*)d_in[0];   // z_e_x   [32768,256]
    const float* cb  = (const float*)d_in[1];   // codebook [1024,256]
    float*       out = (float*)d_out;

    float* ws_csqr = (float*)d_ws;                // [1024]
    float* ws_xsqr = ws_csqr + KCODES;            // [32768]
    short* ws_cbh  = (short*)(ws_xsqr + NROWS);   // [1024*256] bf16 frags

    vq_cbfrag<<<128,        256, 0, stream>>>(cb, ws_cbh);
    vq_csqr  <<<256,        256, 0, stream>>>(cb, ws_csqr);
    vq_xsqr  <<<NROWS / 4,  256, 0, stream>>>(x, ws_xsqr);
    vq_main  <<<NROWS / RPB, 256, 0, stream>>>(x, cb, ws_cbh, ws_csqr, ws_xsqr, out);
}

// Round 14
// 134.718 us; speedup vs baseline: 1.0103x; 1.0103x over previous
//
#include <hip/hip_runtime.h>

// VQEmbedding: B=32,T=1024,D=256,K=1024. N=32768 rows.
// Exact score (proven r2-r13): s = fl32( fl32(csqr_k + xsqr_i) - 2*dot_ik ), argmin,
// first-index ties via packed u64 keys. bf16 MFMA approx (fragment layout verified
// r4-r13); SINGLE-PASS running-threshold filter (r13-verified: halves MFMA, no spill);
// exact fp32 rescore (r2 chain).
// r14 change (ONE delta vs r13 for clean A/B): __launch_bounds__(256,4) -> (256,2).
// r13 post-mortem: the ,4 bound made the allocator crush live set to 64 VGPR ->
// bvA/bvB double-buffer impossible -> B-loads serialized (r5 disease) -> 126us.
// Grid=512 blocks caps at 2 blocks/CU anyway, so ,4 bought nothing. With the 128 cap
// (observed r10/r11) the ~110-reg live set fits -> MLP=8 restored, barrier-free.

#define NROWS  32768
#define DDIM   256
#define KCODES 1024
#define MARGIN 1.5e-3f
#define CAP    2048
#define RPB    64          // rows per block (4 waves x 16 rows)

typedef __attribute__((ext_vector_type(8))) short short8;
typedef __attribute__((ext_vector_type(4))) float f32x4;

__device__ __forceinline__ unsigned short f2bf(float f) {   // RNE f32->bf16
    unsigned u = __float_as_uint(f);
    return (unsigned short)((u + 0x7FFFu + ((u >> 16) & 1u)) >> 16);
}

// exact fp32 dot — BIT-IDENTICAL chain to r2-r13 (proven). DO NOT reorder.
__device__ __forceinline__ float exact_dot(const float* __restrict__ xrow,
                                           const float* __restrict__ crow) {
    const float4* xp = (const float4*)xrow;
    const float4* cp = (const float4*)crow;
    float A = 0.f, B = 0.f;
    #pragma unroll 8
    for (int d4 = 0; d4 < 32; ++d4) {
        float4 xv = xp[d4], cv = cp[d4];
        A = __fmaf_rn(xv.x, cv.x, A);
        A = __fmaf_rn(xv.y, cv.y, A);
        A = __fmaf_rn(xv.z, cv.z, A);
        A = __fmaf_rn(xv.w, cv.w, A);
    }
    #pragma unroll 8
    for (int d4 = 32; d4 < 64; ++d4) {
        float4 xv = xp[d4], cv = cp[d4];
        B = __fmaf_rn(xv.x, cv.x, B);
        B = __fmaf_rn(xv.y, cv.y, B);
        B = __fmaf_rn(xv.z, cv.z, B);
        B = __fmaf_rn(xv.w, cv.w, B);
    }
    return __fadd_rn(A, B);
}

// --- csqr[k] (proven r2-r13, unchanged) ---
__global__ __launch_bounds__(256) void vq_csqr(const float* __restrict__ cb,
                                               float* __restrict__ csqr) {
    int gid  = blockIdx.x * 256 + threadIdx.x;
    int w    = gid >> 6;
    int lane = threadIdx.x & 63;
    if (w >= KCODES) return;
    float4 v = reinterpret_cast<const float4*>(cb)[w * (DDIM / 4) + lane];
    float s = v.x * v.x + v.y * v.y + v.z * v.z + v.w * v.w;
    #pragma unroll
    for (int off = 32; off > 0; off >>= 1) s += __shfl_down(s, off, 64);
    if (lane == 0) csqr[w] = s;
}

// --- xsqr[r] (proven r3-r13, unchanged) ---
__global__ __launch_bounds__(256) void vq_xsqr(const float* __restrict__ x,
                                               float* __restrict__ xsqr) {
    int w = threadIdx.x >> 6, lane = threadIdx.x & 63;
    int row = blockIdx.x * 4 + w;
    float4 v = reinterpret_cast<const float4*>(x + (size_t)row * DDIM)[lane];
    float s = v.x * v.x + v.y * v.y + v.z * v.z + v.w * v.w;
    #pragma unroll
    for (int off = 32; off > 0; off >>= 1) s += __shfl_down(s, off, 64);
    if (lane == 0) xsqr[row] = s;
}

// --- cb -> bf16 B-fragments (layout verified r4-r13): frag(nt,ks): lane l elem i =
//     cb[nt*16 + (l&15)][ks*32 + (l>>4)*8 + i]; linear id = (nt*8+ks)*64 + l ---
__global__ __launch_bounds__(256) void vq_cbfrag(const float* __restrict__ cb,
                                                 short* __restrict__ cbh) {
    int id   = blockIdx.x * 256 + threadIdx.x;
    int lane = id & 63;
    int ks   = (id >> 6) & 7;
    int nt   = id >> 9;
    int code = nt * 16 + (lane & 15);
    int d0   = ks * 32 + (lane >> 4) * 8;
    const float4* p = (const float4*)(cb + (size_t)code * DDIM + d0);
    float4 a = p[0], b = p[1];
    short8 v;
    v[0] = (short)f2bf(a.x); v[1] = (short)f2bf(a.y);
    v[2] = (short)f2bf(a.z); v[3] = (short)f2bf(a.w);
    v[4] = (short)f2bf(b.x); v[5] = (short)f2bf(b.y);
    v[6] = (short)f2bf(b.z); v[7] = (short)f2bf(b.w);
    *(short8*)(cbh + (size_t)id * 8) = v;
}

// --- main: 64 rows/block, 4 waves x 16 rows; each wave scans ALL 64 nt once;
//     barrier-free loop, B double-buffered in registers from L2. ---
__global__ __launch_bounds__(256, 2) void vq_main(const float* __restrict__ x,
                                                  const float* __restrict__ cb,
                                                  const short* __restrict__ cbh,
                                                  const float* __restrict__ csqr,
                                                  const float* __restrict__ xsqr,
                                                  float* __restrict__ out) {
    __shared__ float              csl[KCODES];   // 4KB
    __shared__ unsigned long long keys[RPB];
    __shared__ unsigned           list[CAP];     // 8KB
    __shared__ int                fidx[RPB];
    __shared__ int                cnt, ovf;

    const int t    = threadIdx.x;
    const int lane = t & 63;
    const int w    = t >> 6;         // 0..3 (wave = 16-row tile)
    const int r0   = blockIdx.x * RPB;
    const int lr   = lane & 15;
    const int lg   = lane >> 4;

    ((float4*)csl)[t] = ((const float4*)csqr)[t];
    if (t < RPB) keys[t] = ~0ULL;
    if (t == 0) { cnt = 0; ovf = 0; }
    __syncthreads();                 // init visible (only pre-loop barrier)

    // A-fragments for this wave's 16 rows (mapping identical to r4-r13).
    short8 afr[8];
    {
        const float* xr = x + (size_t)(r0 + w * 16 + lr) * DDIM;
        #pragma unroll
        for (int ks = 0; ks < 8; ++ks) {
            float4 a = *(const float4*)&xr[ks * 32 + lg * 8];
            float4 b = *(const float4*)&xr[ks * 32 + lg * 8 + 4];
            short8 v;
            v[0] = (short)f2bf(a.x); v[1] = (short)f2bf(a.y);
            v[2] = (short)f2bf(a.z); v[3] = (short)f2bf(a.w);
            v[4] = (short)f2bf(b.x); v[5] = (short)f2bf(b.y);
            v[6] = (short)f2bf(b.z); v[7] = (short)f2bf(b.w);
            afr[ks] = v;
        }
    }

    const short8* cbh8 = (const short8*)cbh;
    auto load_bv = [&](short8 (&bv)[8], int nt) {
        const short8* bp = cbh8 + (size_t)(nt * 8) * 64 + lane;
        #pragma unroll
        for (int ks = 0; ks < 8; ++ks) bv[ks] = bp[(size_t)ks * 64];
    };

    float runm[4] = {__builtin_inff(), __builtin_inff(), __builtin_inff(), __builtin_inff()};

    // single pass over all 64 code-tiles: score -> row-min butterfly -> running
    // threshold append. No barriers; appends via LDS atomics.
    auto tile_step = [&](const short8 (&bv)[8], int nt) {
        f32x4 af = (f32x4){0.f, 0.f, 0.f, 0.f};
        #pragma unroll
        for (int ks = 0; ks < 8; ++ks)
            af = __builtin_amdgcn_mfma_f32_16x16x32_bf16(afr[ks], bv[ks], af, 0, 0, 0);
        const int code = nt * 16 + lr;
        const float cs1 = __fadd_rn(csl[code], 1.0f);   // +1 shift (uniform, proven form)
        float s[4];
        #pragma unroll
        for (int j = 0; j < 4; ++j) {
            s[j] = __fmaf_rn(-2.f, af[j], cs1);
            float v = s[j];
            v = fminf(v, __shfl_xor(v, 1, 64));
            v = fminf(v, __shfl_xor(v, 2, 64));
            v = fminf(v, __shfl_xor(v, 4, 64));
            v = fminf(v, __shfl_xor(v, 8, 64));   // row-min of this tile
            runm[j] = fminf(runm[j], v);
            if (s[j] <= runm[j] + MARGIN) {
                int row = w * 16 + lg * 4 + j;
                int pos = atomicAdd(&cnt, 1);
                if (pos < CAP) list[pos] = ((unsigned)row << 10) | (unsigned)code;
                else ovf = 1;
            }
        }
    };

    short8 bvA[8], bvB[8];
    load_bv(bvA, 0);
    for (int c = 0; c < 64; c += 2) {
        load_bv(bvB, c + 1);
        tile_step(bvA, c);
        if (c + 2 < 64) load_bv(bvA, c + 2);
        tile_step(bvB, c + 1);
    }
    __syncthreads();   // all candidates in list

    // ---- exact rescore (r2-proven chain + grid formula), u64 first-index argmin ----
    if (ovf || cnt > CAP) {
        for (int it = t; it < RPB * KCODES; it += 256) {   // safety net (never fires)
            int row = it >> 10, code = it & (KCODES - 1);
            float dot = exact_dot(x + (size_t)(r0 + row) * DDIM, cb + (size_t)code * DDIM);
            float s   = __fmaf_rn(-2.f, dot, __fadd_rn(csl[code], xsqr[r0 + row]));
            atomicMin(&keys[row], ((unsigned long long)__float_as_uint(s) << 32) | (unsigned)code);
        }
    } else {
        for (int i = t; i < cnt; i += 256) {
            unsigned e = list[i];
            int row = (int)(e >> 10), code = (int)(e & 0x3FFu);
            float dot = exact_dot(x + (size_t)(r0 + row) * DDIM, cb + (size_t)code * DDIM);
            float s   = __fmaf_rn(-2.f, dot, __fadd_rn(csl[code], xsqr[r0 + row]));
            atomicMin(&keys[row], ((unsigned long long)__float_as_uint(s) << 32) | (unsigned)code);
        }
    }
    __syncthreads();

    if (t < RPB) {
        int code = (int)(unsigned)(keys[t] & 0xffffffffu);
        fidx[t] = code;
        out[(size_t)2 * NROWS * DDIM + (r0 + t)] = (float)code;
    }
    __syncthreads();

    // gather winning codes: 64 rows x 64 float4, coalesced
    const float4* cb4  = (const float4*)cb;
    float4*       out0 = (float4*)out;
    float4*       out1 = out0 + (size_t)NROWS * (DDIM / 4);
    #pragma unroll
    for (int i = 0; i < 16; ++i) {
        int it  = i * 256 + t;
        int row = it >> 6, col = it & 63;
        float4 v = cb4[(size_t)fidx[row] * (DDIM / 4) + col];
        size_t o = (size_t)(r0 + row) * (DDIM / 4) + col;
        out0[o] = v;
        out1[o] = v;
    }
}

extern "C" void kernel_launch(void* const* d_in, const int* in_sizes, int n_in,
                              void* d_out, int out_size, void* d_ws, size_t ws_size,
                              hipStream_t stream) {
    const float* x   = (const float*)d_in[0];   // z_e_x   [32768,256]
    const float* cb  = (const float*)d_in[1];   // codebook [1024,256]
    float*       out = (float*)d_out;

    float* ws_csqr = (float*)d_ws;                // [1024]
    float* ws_xsqr = ws_csqr + KCODES;            // [32768]
    short* ws_cbh  = (short*)(ws_xsqr + NROWS);   // [1024*256] bf16 frags

    vq_cbfrag<<<128,        256, 0, stream>>>(cb, ws_cbh);
    vq_csqr  <<<256,        256, 0, stream>>>(cb, ws_csqr);
    vq_xsqr  <<<NROWS / 4,  256, 0, stream>>>(x, ws_xsqr);
    vq_main  <<<NROWS / RPB, 256, 0, stream>>>(x, cb, ws_cbh, ws_csqr, ws_xsqr, out);
}

// Round 15
// 131.836 us; speedup vs baseline: 1.0323x; 1.0219x over previous
//
#include <hip/hip_runtime.h>

// VQEmbedding: B=32,T=1024,D=256,K=1024. N=32768 rows.
// Exact score (proven r2-r14): s = fl32( fl32(csqr_k + xsqr_i) - 2*dot_ik ), argmin,
// first-index ties via packed u64 keys. bf16 MFMA approx (fragment layout verified
// r4-r14); SINGLE-PASS running-threshold filter (r13/r14-verified: halves MFMA, no
// spill); exact fp32 rescore (r2 chain).
// r15 change (ONE mechanism vs r14): B-tile loads via inline-asm global_load_dwordx4
// with 4 named register buffers, prefetch distance 2, counted s_waitcnt vmcnt(16)
// (never 0 in steady state) + sched_barrier(0) before consume (rule #18).
// r14 post-mortem: compiler sank each load next to its MFMA (VGPR=68) -> serialized
// L2 latency 350cy x 8 x 64 tiles dominated. asm volatile loads cannot be sunk;
// vmcnt counting keeps 2 tiles (16 loads) in flight -> L2-BW bound (~30us/CU floor).

#define NROWS  32768
#define DDIM   256
#define KCODES 1024
#define MARGIN 1.5e-3f
#define CAP    2048
#define RPB    64          // rows per block (4 waves x 16 rows)

typedef __attribute__((ext_vector_type(8))) short short8;
typedef __attribute__((ext_vector_type(4))) float f32x4;

__device__ __forceinline__ unsigned short f2bf(float f) {   // RNE f32->bf16
    unsigned u = __float_as_uint(f);
    return (unsigned short)((u + 0x7FFFu + ((u >> 16) & 1u)) >> 16);
}

// exact fp32 dot — BIT-IDENTICAL chain to r2-r14 (proven). DO NOT reorder.
__device__ __forceinline__ float exact_dot(const float* __restrict__ xrow,
                                           const float* __restrict__ crow) {
    const float4* xp = (const float4*)xrow;
    const float4* cp = (const float4*)crow;
    float A = 0.f, B = 0.f;
    #pragma unroll 8
    for (int d4 = 0; d4 < 32; ++d4) {
        float4 xv = xp[d4], cv = cp[d4];
        A = __fmaf_rn(xv.x, cv.x, A);
        A = __fmaf_rn(xv.y, cv.y, A);
        A = __fmaf_rn(xv.z, cv.z, A);
        A = __fmaf_rn(xv.w, cv.w, A);
    }
    #pragma unroll 8
    for (int d4 = 32; d4 < 64; ++d4) {
        float4 xv = xp[d4], cv = cp[d4];
        B = __fmaf_rn(xv.x, cv.x, B);
        B = __fmaf_rn(xv.y, cv.y, B);
        B = __fmaf_rn(xv.z, cv.z, B);
        B = __fmaf_rn(xv.w, cv.w, B);
    }
    return __fadd_rn(A, B);
}

// --- csqr[k] (proven r2-r14, unchanged) ---
__global__ __launch_bounds__(256) void vq_csqr(const float* __restrict__ cb,
                                               float* __restrict__ csqr) {
    int gid  = blockIdx.x * 256 + threadIdx.x;
    int w    = gid >> 6;
    int lane = threadIdx.x & 63;
    if (w >= KCODES) return;
    float4 v = reinterpret_cast<const float4*>(cb)[w * (DDIM / 4) + lane];
    float s = v.x * v.x + v.y * v.y + v.z * v.z + v.w * v.w;
    #pragma unroll
    for (int off = 32; off > 0; off >>= 1) s += __shfl_down(s, off, 64);
    if (lane == 0) csqr[w] = s;
}

// --- xsqr[r] (proven r3-r14, unchanged) ---
__global__ __launch_bounds__(256) void vq_xsqr(const float* __restrict__ x,
                                               float* __restrict__ xsqr) {
    int w = threadIdx.x >> 6, lane = threadIdx.x & 63;
    int row = blockIdx.x * 4 + w;
    float4 v = reinterpret_cast<const float4*>(x + (size_t)row * DDIM)[lane];
    float s = v.x * v.x + v.y * v.y + v.z * v.z + v.w * v.w;
    #pragma unroll
    for (int off = 32; off > 0; off >>= 1) s += __shfl_down(s, off, 64);
    if (lane == 0) xsqr[row] = s;
}

// --- cb -> bf16 B-fragments (layout verified r4-r14): frag(nt,ks): lane l elem i =
//     cb[nt*16 + (l&15)][ks*32 + (l>>4)*8 + i]; linear id = (nt*8+ks)*64 + l ---
__global__ __launch_bounds__(256) void vq_cbfrag(const float* __restrict__ cb,
                                                 short* __restrict__ cbh) {
    int id   = blockIdx.x * 256 + threadIdx.x;
    int lane = id & 63;
    int ks   = (id >> 6) & 7;
    int nt   = id >> 9;
    int code = nt * 16 + (lane & 15);
    int d0   = ks * 32 + (lane >> 4) * 8;
    const float4* p = (const float4*)(cb + (size_t)code * DDIM + d0);
    float4 a = p[0], b = p[1];
    short8 v;
    v[0] = (short)f2bf(a.x); v[1] = (short)f2bf(a.y);
    v[2] = (short)f2bf(a.z); v[3] = (short)f2bf(a.w);
    v[4] = (short)f2bf(b.x); v[5] = (short)f2bf(b.y);
    v[6] = (short)f2bf(b.z); v[7] = (short)f2bf(b.w);
    *(short8*)(cbh + (size_t)id * 8) = v;
}

// issue one B-tile (8 x 16B) into a named register buffer; asm volatile so the
// scheduler cannot sink/serialize. Byte offsets ks*1024 split across 2 addr regs
// (13-bit signed offset limit).
#define ISSUE(P, n) do {                                                     \
    const char* _a0 = base + (size_t)(n) * 8192;                             \
    const char* _a1 = _a0 + 4096;                                            \
    asm volatile(                                                            \
        "global_load_dwordx4 %0, %8, off\n\t"                                \
        "global_load_dwordx4 %1, %8, off offset:1024\n\t"                    \
        "global_load_dwordx4 %2, %8, off offset:2048\n\t"                    \
        "global_load_dwordx4 %3, %8, off offset:3072\n\t"                    \
        "global_load_dwordx4 %4, %9, off\n\t"                                \
        "global_load_dwordx4 %5, %9, off offset:1024\n\t"                    \
        "global_load_dwordx4 %6, %9, off offset:2048\n\t"                    \
        "global_load_dwordx4 %7, %9, off offset:3072"                        \
        : "=&v"(P[0]), "=&v"(P[1]), "=&v"(P[2]), "=&v"(P[3]),                \
          "=&v"(P[4]), "=&v"(P[5]), "=&v"(P[6]), "=&v"(P[7])                 \
        : "v"(_a0), "v"(_a1));                                               \
} while (0)

// counted waits: never 0 in steady state (2 tiles = 16 loads stay in flight).
// sched_barrier(0) after each wait: hipcc hoists reg-only MFMA past inline-asm
// waitcnt otherwise (rule #18).
#define WAITN(N) do {                                                        \
    asm volatile("s_waitcnt vmcnt(" #N ")" ::: "memory");                    \
    __builtin_amdgcn_sched_barrier(0);                                       \
} while (0)

// --- main: 64 rows/block, 4 waves x 16 rows; each wave scans ALL 64 nt once;
//     barrier-free loop; B pipelined 2-deep in asm-loaded register buffers. ---
__global__ __launch_bounds__(256, 2) void vq_main(const float* __restrict__ x,
                                                  const float* __restrict__ cb,
                                                  const short* __restrict__ cbh,
                                                  const float* __restrict__ csqr,
                                                  const float* __restrict__ xsqr,
                                                  float* __restrict__ out) {
    __shared__ float              csl[KCODES];   // 4KB
    __shared__ unsigned long long keys[RPB];
    __shared__ unsigned           list[CAP];     // 8KB
    __shared__ int                fidx[RPB];
    __shared__ int                cnt, ovf;

    const int t    = threadIdx.x;
    const int lane = t & 63;
    const int w    = t >> 6;         // 0..3 (wave = 16-row tile)
    const int r0   = blockIdx.x * RPB;
    const int lr   = lane & 15;
    const int lg   = lane >> 4;

    ((float4*)csl)[t] = ((const float4*)csqr)[t];
    if (t < RPB) keys[t] = ~0ULL;
    if (t == 0) { cnt = 0; ovf = 0; }
    __syncthreads();                 // init visible (only pre-loop barrier)

    // A-fragments for this wave's 16 rows (mapping identical to r4-r14).
    short8 afr[8];
    {
        const float* xr = x + (size_t)(r0 + w * 16 + lr) * DDIM;
        #pragma unroll
        for (int ks = 0; ks < 8; ++ks) {
            float4 a = *(const float4*)&xr[ks * 32 + lg * 8];
            float4 b = *(const float4*)&xr[ks * 32 + lg * 8 + 4];
            short8 v;
            v[0] = (short)f2bf(a.x); v[1] = (short)f2bf(a.y);
            v[2] = (short)f2bf(a.z); v[3] = (short)f2bf(a.w);
            v[4] = (short)f2bf(b.x); v[5] = (short)f2bf(b.y);
            v[6] = (short)f2bf(b.z); v[7] = (short)f2bf(b.w);
            afr[ks] = v;
        }
    }

    float runm[4] = {__builtin_inff(), __builtin_inff(), __builtin_inff(), __builtin_inff()};

    // score one tile: 8 MFMAs + row-min butterfly + running-threshold append
    // (bit-identical to r13/r14's tile_step).
    auto tile_step = [&](const short8 (&bv)[8], int nt) {
        f32x4 af = (f32x4){0.f, 0.f, 0.f, 0.f};
        #pragma unroll
        for (int ks = 0; ks < 8; ++ks)
            af = __builtin_amdgcn_mfma_f32_16x16x32_bf16(afr[ks], bv[ks], af, 0, 0, 0);
        const int code = nt * 16 + lr;
        const float cs1 = __fadd_rn(csl[code], 1.0f);   // +1 shift (uniform, proven form)
        float s[4];
        #pragma unroll
        for (int j = 0; j < 4; ++j) {
            s[j] = __fmaf_rn(-2.f, af[j], cs1);
            float v = s[j];
            v = fminf(v, __shfl_xor(v, 1, 64));
            v = fminf(v, __shfl_xor(v, 2, 64));
            v = fminf(v, __shfl_xor(v, 4, 64));
            v = fminf(v, __shfl_xor(v, 8, 64));   // row-min of this tile
            runm[j] = fminf(runm[j], v);
            if (s[j] <= runm[j] + MARGIN) {
                int row = w * 16 + lg * 4 + j;
                int pos = atomicAdd(&cnt, 1);
                if (pos < CAP) list[pos] = ((unsigned)row << 10) | (unsigned)code;
                else ovf = 1;
            }
        }
    };

    // ---- pipelined scan: 4 named buffers, prefetch distance 2, vmcnt(16) ----
    const char* base = (const char*)cbh + (size_t)lane * 16;
    short8 p0[8], p1[8], p2[8], p3[8];

    asm volatile("s_waitcnt vmcnt(0)" ::: "memory");   // clean count before pipeline
    ISSUE(p0, 0);
    ISSUE(p1, 1);
    for (int k = 0; k < 15; ++k) {
        const int n = k * 4;
        ISSUE(p2, n + 2); WAITN(16); tile_step(p0, n + 0);
        ISSUE(p3, n + 3); WAITN(16); tile_step(p1, n + 1);
        ISSUE(p0, n + 4); WAITN(16); tile_step(p2, n + 2);
        ISSUE(p1, n + 5); WAITN(16); tile_step(p3, n + 3);
    }
    // drain: tiles 60,61 already in flight from k=14
    ISSUE(p2, 62); WAITN(16); tile_step(p0, 60);
    ISSUE(p3, 63); WAITN(16); tile_step(p1, 61);
    WAITN(8);  tile_step(p2, 62);
    WAITN(0);  tile_step(p3, 63);

    __syncthreads();   // all candidates in list

    // ---- exact rescore (r2-proven chain + grid formula), u64 first-index argmin ----
    if (ovf || cnt > CAP) {
        for (int it = t; it < RPB * KCODES; it += 256) {   // safety net (never fires)
            int row = it >> 10, code = it & (KCODES - 1);
            float dot = exact_dot(x + (size_t)(r0 + row) * DDIM, cb + (size_t)code * DDIM);
            float s   = __fmaf_rn(-2.f, dot, __fadd_rn(csl[code], xsqr[r0 + row]));
            atomicMin(&keys[row], ((unsigned long long)__float_as_uint(s) << 32) | (unsigned)code);
        }
    } else {
        for (int i = t; i < cnt; i += 256) {
            unsigned e = list[i];
            int row = (int)(e >> 10), code = (int)(e & 0x3FFu);
            float dot = exact_dot(x + (size_t)(r0 + row) * DDIM, cb + (size_t)code * DDIM);
            float s   = __fmaf_rn(-2.f, dot, __fadd_rn(csl[code], xsqr[r0 + row]));
            atomicMin(&keys[row], ((unsigned long long)__float_as_uint(s) << 32) | (unsigned)code);
        }
    }
    __syncthreads();

    if (t < RPB) {
        int code = (int)(unsigned)(keys[t] & 0xffffffffu);
        fidx[t] = code;
        out[(size_t)2 * NROWS * DDIM + (r0 + t)] = (float)code;
    }
    __syncthreads();

    // gather winning codes: 64 rows x 64 float4, coalesced
    const float4* cb4  = (const float4*)cb;
    float4*       out0 = (float4*)out;
    float4*       out1 = out0 + (size_t)NROWS * (DDIM / 4);
    #pragma unroll
    for (int i = 0; i < 16; ++i) {
        int it  = i * 256 + t;
        int row = it >> 6, col = it & 63;
        float4 v = cb4[(size_t)fidx[row] * (DDIM / 4) + col];
        size_t o = (size_t)(r0 + row) * (DDIM / 4) + col;
        out0[o] = v;
        out1[o] = v;
    }
}

extern "C" void kernel_launch(void* const* d_in, const int* in_sizes, int n_in,
                              void* d_out, int out_size, void* d_ws, size_t ws_size,
                              hipStream_t stream) {
    const float* x   = (const float*)d_in[0];   // z_e_x   [32768,256]
    const float* cb  = (const float*)d_in[1];   // codebook [1024,256]
    float*       out = (float*)d_out;

    float* ws_csqr = (float*)d_ws;                // [1024]
    float* ws_xsqr = ws_csqr + KCODES;            // [32768]
    short* ws_cbh  = (short*)(ws_xsqr + NROWS);   // [1024*256] bf16 frags

    vq_cbfrag<<<128,        256, 0, stream>>>(cb, ws_cbh);
    vq_csqr  <<<256,        256, 0, stream>>>(cb, ws_csqr);
    vq_xsqr  <<<NROWS / 4,  256, 0, stream>>>(x, ws_xsqr);
    vq_main  <<<NROWS / RPB, 256, 0, stream>>>(x, cb, ws_cbh, ws_csqr, ws_xsqr, out);
}

// Round 16
// 120.521 us; speedup vs baseline: 1.1293x; 1.0939x over previous
//
#include <hip/hip_runtime.h>

// VQEmbedding: B=32,T=1024,D=256,K=1024. N=32768 rows.
// Exact score (proven r2-r15): s = fl32( fl32(csqr_k + xsqr_i) - 2*dot_ik ), argmin,
// first-index ties via packed u64 keys. bf16 MFMA approx (layout verified r4-r15).
// r16 = the measured-optimal combination:
//  - r9's LDS-shared staged scan (4 waves share B chunks; 256MB L2 traffic, 37us/pass)
//    run ONCE (r13-proven single-pass running-threshold filter, half the MFMA);
//  - candidates carry a 16-bit truncated fixed-point score; post-filter against the
//    FINAL per-row threshold cuts rescores ~350 -> ~77/block (r15 ledger: the 37us
//    r9->r13 regression was divergent-rescore transactions, 128 instr x 64 lanes each).
//  - exact fp32 rescore (r2 chain) only for survivors; u64 atomicMin tie-break.
// Conservative filter: trunc quantization is monotone -> s<=thr => q(s)<=q(thr);
// clamps at both ends keep the superset property. Overflow -> exact brute force.

#define NROWS  32768
#define DDIM   256
#define KCODES 1024
#define MARGIN 1.5e-3f
#define CAP    1536
#define RPB    64          // rows per block (4 waves x 16 rows)
#define NCHUNK 16          // chunks; chunk = 4 nt = 64 codes = 32KB frags

typedef __attribute__((ext_vector_type(8))) short short8;
typedef __attribute__((ext_vector_type(4))) float f32x4;

__device__ __forceinline__ unsigned short f2bf(float f) {   // RNE f32->bf16
    unsigned u = __float_as_uint(f);
    return (unsigned short)((u + 0x7FFFu + ((u >> 16) & 1u)) >> 16);
}

// 16-bit fixed-point score quantizer (trunc): monotone, clamped both ends.
__device__ __forceinline__ unsigned qscore(float s) {
    float f = (s - 0.75f) * 131072.0f;     // s in ~[0.97,1.03]; grid 7.6e-6 << MARGIN
    if (f <= 0.f) return 0u;
    if (f >= 65535.f) return 65535u;
    return (unsigned)f;
}

// exact fp32 dot — BIT-IDENTICAL chain to r2-r15 (proven). DO NOT reorder.
__device__ __forceinline__ float exact_dot(const float* __restrict__ xrow,
                                           const float* __restrict__ crow) {
    const float4* xp = (const float4*)xrow;
    const float4* cp = (const float4*)crow;
    float A = 0.f, B = 0.f;
    #pragma unroll 8
    for (int d4 = 0; d4 < 32; ++d4) {
        float4 xv = xp[d4], cv = cp[d4];
        A = __fmaf_rn(xv.x, cv.x, A);
        A = __fmaf_rn(xv.y, cv.y, A);
        A = __fmaf_rn(xv.z, cv.z, A);
        A = __fmaf_rn(xv.w, cv.w, A);
    }
    #pragma unroll 8
    for (int d4 = 32; d4 < 64; ++d4) {
        float4 xv = xp[d4], cv = cp[d4];
        B = __fmaf_rn(xv.x, cv.x, B);
        B = __fmaf_rn(xv.y, cv.y, B);
        B = __fmaf_rn(xv.z, cv.z, B);
        B = __fmaf_rn(xv.w, cv.w, B);
    }
    return __fadd_rn(A, B);
}

// --- csqr[k] (proven r2-r15, unchanged) ---
__global__ __launch_bounds__(256) void vq_csqr(const float* __restrict__ cb,
                                               float* __restrict__ csqr) {
    int gid  = blockIdx.x * 256 + threadIdx.x;
    int w    = gid >> 6;
    int lane = threadIdx.x & 63;
    if (w >= KCODES) return;
    float4 v = reinterpret_cast<const float4*>(cb)[w * (DDIM / 4) + lane];
    float s = v.x * v.x + v.y * v.y + v.z * v.z + v.w * v.w;
    #pragma unroll
    for (int off = 32; off > 0; off >>= 1) s += __shfl_down(s, off, 64);
    if (lane == 0) csqr[w] = s;
}

// --- xsqr[r] (proven r3-r15, unchanged) ---
__global__ __launch_bounds__(256) void vq_xsqr(const float* __restrict__ x,
                                               float* __restrict__ xsqr) {
    int w = threadIdx.x >> 6, lane = threadIdx.x & 63;
    int row = blockIdx.x * 4 + w;
    float4 v = reinterpret_cast<const float4*>(x + (size_t)row * DDIM)[lane];
    float s = v.x * v.x + v.y * v.y + v.z * v.z + v.w * v.w;
    #pragma unroll
    for (int off = 32; off > 0; off >>= 1) s += __shfl_down(s, off, 64);
    if (lane == 0) xsqr[row] = s;
}

// --- cb -> bf16 B-fragments (layout verified r4-r15): frag(nt,ks): lane l elem i =
//     cb[nt*16 + (l&15)][ks*32 + (l>>4)*8 + i]; linear id = (nt*8+ks)*64 + l ---
__global__ __launch_bounds__(256) void vq_cbfrag(const float* __restrict__ cb,
                                                 short* __restrict__ cbh) {
    int id   = blockIdx.x * 256 + threadIdx.x;
    int lane = id & 63;
    int ks   = (id >> 6) & 7;
    int nt   = id >> 9;
    int code = nt * 16 + (lane & 15);
    int d0   = ks * 32 + (lane >> 4) * 8;
    const float4* p = (const float4*)(cb + (size_t)code * DDIM + d0);
    float4 a = p[0], b = p[1];
    short8 v;
    v[0] = (short)f2bf(a.x); v[1] = (short)f2bf(a.y);
    v[2] = (short)f2bf(a.z); v[3] = (short)f2bf(a.w);
    v[4] = (short)f2bf(b.x); v[5] = (short)f2bf(b.y);
    v[6] = (short)f2bf(b.z); v[7] = (short)f2bf(b.w);
    *(short8*)(cbh + (size_t)id * 8) = v;
}

// --- main: 64 rows/block, 4 waves x 16 rows; B LDS-shared double-buffered (r9 staging,
//     proven 86us structure), SINGLE pass with running-threshold append + post-filter ---
__global__ __launch_bounds__(256, 2) void vq_main(const float* __restrict__ x,
                                                  const float* __restrict__ cb,
                                                  const short* __restrict__ cbh,
                                                  const float* __restrict__ csqr,
                                                  const float* __restrict__ xsqr,
                                                  float* __restrict__ out) {
    __shared__ short              bstage[2][4 * 8 * 64 * 8];  // 2 x 32KB B chunks
    __shared__ float              csl[KCODES];                // 4KB
    __shared__ unsigned long long keys[RPB];
    __shared__ unsigned           list[CAP];                  // 6KB, (q<<16)|(row<<10)|code
    __shared__ unsigned           qthrl[RPB];
    __shared__ int                fidx[RPB];
    __shared__ int                cnt, ovf;

    const int t    = threadIdx.x;
    const int lane = t & 63;
    const int w    = t >> 6;         // 0..3 (wave = 16-row tile)
    const int r0   = blockIdx.x * RPB;
    const int lr   = lane & 15;
    const int lg   = lane >> 4;

    ((float4*)csl)[t] = ((const float4*)csqr)[t];
    if (t < RPB) keys[t] = ~0ULL;
    if (t == 0) { cnt = 0; ovf = 0; }

    // A-fragments for this wave's 16 rows (mapping identical to r4-r15).
    short8 afr[8];
    {
        const float* xr = x + (size_t)(r0 + w * 16 + lr) * DDIM;
        #pragma unroll
        for (int ks = 0; ks < 8; ++ks) {
            float4 a = *(const float4*)&xr[ks * 32 + lg * 8];
            float4 b = *(const float4*)&xr[ks * 32 + lg * 8 + 4];
            short8 v;
            v[0] = (short)f2bf(a.x); v[1] = (short)f2bf(a.y);
            v[2] = (short)f2bf(a.z); v[3] = (short)f2bf(a.w);
            v[4] = (short)f2bf(b.x); v[5] = (short)f2bf(b.y);
            v[6] = (short)f2bf(b.z); v[7] = (short)f2bf(b.w);
            afr[ks] = v;
        }
    }

    const short8* cbh8 = (const short8*)cbh;   // fragment-linear, 16B units

    // T14 pipeline state (r9-proven): pf holds chunk (c+1) while computing chunk c.
    short8 pf[8];
    #pragma unroll
    for (int i = 0; i < 8; ++i) pf[i] = cbh8[(size_t)0 * 2048 + i * 256 + t];   // chunk 0
    {   // write chunk 0 -> buf0, start chunk 1 loads
        short8* dst = (short8*)bstage[0];
        #pragma unroll
        for (int i = 0; i < 8; ++i) dst[i * 256 + t] = pf[i];
        #pragma unroll
        for (int i = 0; i < 8; ++i) pf[i] = cbh8[(size_t)1 * 2048 + i * 256 + t];   // chunk 1
    }
    __syncthreads();

    float runm[4] = {__builtin_inff(), __builtin_inff(), __builtin_inff(), __builtin_inff()};

    for (int c = 0; c < NCHUNK; ++c) {
        // 1) write prefetched chunk c+1 into the buffer read LAST iter
        if (c + 1 < NCHUNK) {
            short8* dst = (short8*)bstage[(c + 1) & 1];
            #pragma unroll
            for (int i = 0; i < 8; ++i) dst[i * 256 + t] = pf[i];
        }
        // 2) issue global loads for chunk c+2 (latency hides under compute)
        if (c + 2 < NCHUNK) {
            const size_t cb2 = (size_t)(c + 2) * 2048;
            #pragma unroll
            for (int i = 0; i < 8; ++i) pf[i] = cbh8[cb2 + i * 256 + t];
        }
        // 3) compute chunk c from buf[c&1]: 4 nt tiles, single-pass epilogue
        const short* bs = bstage[c & 1];
        #pragma unroll
        for (int m = 0; m < 4; ++m) {
            const int nt = c * 4 + m;
            short8 bv[8];
            #pragma unroll
            for (int ks = 0; ks < 8; ++ks)
                bv[ks] = *(const short8*)&bs[((m * 8 + ks) * 64 + lane) * 8];
            f32x4 af = (f32x4){0.f, 0.f, 0.f, 0.f};
            #pragma unroll
            for (int ks = 0; ks < 8; ++ks)
                af = __builtin_amdgcn_mfma_f32_16x16x32_bf16(afr[ks], bv[ks], af, 0, 0, 0);

            const int code = nt * 16 + lr;
            const float cs1 = __fadd_rn(csl[code], 1.0f);   // +1: score>0 (proven form)
            #pragma unroll
            for (int j = 0; j < 4; ++j) {
                float s = __fmaf_rn(-2.f, af[j], cs1);
                float v = s;
                v = fminf(v, __shfl_xor(v, 1, 64));
                v = fminf(v, __shfl_xor(v, 2, 64));
                v = fminf(v, __shfl_xor(v, 4, 64));
                v = fminf(v, __shfl_xor(v, 8, 64));   // row-min of this tile
                runm[j] = fminf(runm[j], v);
                if (s <= runm[j] + MARGIN) {          // running threshold (r13-proven)
                    int row = w * 16 + lg * 4 + j;
                    int pos = atomicAdd(&cnt, 1);
                    if (pos < CAP) list[pos] = (qscore(s) << 16) | ((unsigned)row << 10) | (unsigned)code;
                    else ovf = 1;
                }
            }
        }
        __syncthreads();   // chunk c+1 visible; buf[c&1] readers done
    }

    // final per-row quantized thresholds (runm = true row min, uniform across lr lanes)
    if (lr == 0) {
        #pragma unroll
        for (int j = 0; j < 4; ++j)
            qthrl[w * 16 + lg * 4 + j] = qscore(runm[j] + MARGIN);
    }
    __syncthreads();

    // ---- post-filter + exact rescore (r2-proven chain + grid formula) ----
    if (ovf || cnt > CAP) {
        for (int it = t; it < RPB * KCODES; it += 256) {   // safety net
            int row = it >> 10, code = it & (KCODES - 1);
            float dot = exact_dot(x + (size_t)(r0 + row) * DDIM, cb + (size_t)code * DDIM);
            float s   = __fmaf_rn(-2.f, dot, __fadd_rn(csl[code], xsqr[r0 + row]));
            atomicMin(&keys[row], ((unsigned long long)__float_as_uint(s) << 32) | (unsigned)code);
        }
    } else {
        for (int i = t; i < cnt; i += 256) {
            unsigned e   = list[i];
            int row      = (int)((e >> 10) & 63u);
            if ((e >> 16) > qthrl[row]) continue;          // conservative final filter
            int code     = (int)(e & 0x3FFu);
            float dot = exact_dot(x + (size_t)(r0 + row) * DDIM, cb + (size_t)code * DDIM);
            float s   = __fmaf_rn(-2.f, dot, __fadd_rn(csl[code], xsqr[r0 + row]));
            atomicMin(&keys[row], ((unsigned long long)__float_as_uint(s) << 32) | (unsigned)code);
        }
    }
    __syncthreads();

    if (t < RPB) {
        int code = (int)(unsigned)(keys[t] & 0xffffffffu);
        fidx[t] = code;
        out[(size_t)2 * NROWS * DDIM + (r0 + t)] = (float)code;
    }
    __syncthreads();

    // gather winning codes: 64 rows x 64 float4, coalesced
    const float4* cb4  = (const float4*)cb;
    float4*       out0 = (float4*)out;
    float4*       out1 = out0 + (size_t)NROWS * (DDIM / 4);
    #pragma unroll
    for (int i = 0; i < 16; ++i) {
        int it  = i * 256 + t;
        int row = it >> 6, col = it & 63;
        float4 v = cb4[(size_t)fidx[row] * (DDIM / 4) + col];
        size_t o = (size_t)(r0 + row) * (DDIM / 4) + col;
        out0[o] = v;
        out1[o] = v;
    }
}

extern "C" void kernel_launch(void* const* d_in, const int* in_sizes, int n_in,
                              void* d_out, int out_size, void* d_ws, size_t ws_size,
                              hipStream_t stream) {
    const float* x   = (const float*)d_in[0];   // z_e_x   [32768,256]
    const float* cb  = (const float*)d_in[1];   // codebook [1024,256]
    float*       out = (float*)d_out;

    float* ws_csqr = (float*)d_ws;                // [1024]
    float* ws_xsqr = ws_csqr + KCODES;            // [32768]
    short* ws_cbh  = (short*)(ws_xsqr + NROWS);   // [1024*256] bf16 frags

    vq_cbfrag<<<128,        256, 0, stream>>>(cb, ws_cbh);
    vq_csqr  <<<256,        256, 0, stream>>>(cb, ws_csqr);
    vq_xsqr  <<<NROWS / 4,  256, 0, stream>>>(x, ws_xsqr);
    vq_main  <<<NROWS / RPB, 256, 0, stream>>>(x, cb, ws_cbh, ws_csqr, ws_xsqr, out);
}

// Round 17
// 120.343 us; speedup vs baseline: 1.1309x; 1.0015x over previous
//
#include <hip/hip_runtime.h>

// VQEmbedding: B=32,T=1024,D=256,K=1024. N=32768 rows.
// Exact score (proven r2-r16): s = fl32( fl32(csqr_k + xsqr_i) - 2*dot_ik ), argmin,
// first-index ties via packed u64 keys. bf16 MFMA approx; exact fp32 rescore (r2 chain).
// r17 change (r16 ledger: per-tile 4-deep shfl butterfly = 64 shfls/chunk x ~120cy
// single-outstanding DS latency = +3.2us/iter — THE r13-r16 disease):
//  - SWAPPED MFMA operands: mfma(bv, afr, acc) -> D[code][row]; lane (lg,lr) holds
//    4 codes of ONE row lr => per-tile epilogue is pure VALU (3 fmin + 1 update +
//    4 tests), ZERO shuffles. Same register fragments (A/B layouts identical).
//  - lane-local running threshold (sound: winner s<=runm_lane; ties <=gmin+2eps<=runm+M)
//    + 4-tile min-only priming (appends ~900/block); 2 shfls ONCE for final row min.
//  - r9's proven LDS staging pipeline, SINGLE pass; r16's qscore post-filter (~85
//    rescores); 16-point exact self-check -> brute-force fallback if orientation wrong.

#define NROWS  32768
#define DDIM   256
#define KCODES 1024
#define MARGIN 1.5e-3f
#define CHKTHR 2.5e-3f
#define CAP    2048
#define RPB    64          // rows per block (4 waves x 16 rows)
#define NCHUNK 16          // chunk = 4 nt = 64 codes = 32KB frags

typedef __attribute__((ext_vector_type(8))) short short8;
typedef __attribute__((ext_vector_type(4))) float f32x4;

__device__ __forceinline__ unsigned short f2bf(float f) {   // RNE f32->bf16
    unsigned u = __float_as_uint(f);
    return (unsigned short)((u + 0x7FFFu + ((u >> 16) & 1u)) >> 16);
}

// 16-bit fixed-point score quantizer (trunc): monotone, clamped (proven r16).
__device__ __forceinline__ unsigned qscore(float s) {
    float f = (s - 0.75f) * 131072.0f;     // s in ~[0.97,1.03]; grid 7.6e-6 << MARGIN
    if (f <= 0.f) return 0u;
    if (f >= 65535.f) return 65535u;
    return (unsigned)f;
}

// exact fp32 dot — BIT-IDENTICAL chain to r2-r16 (proven). DO NOT reorder.
__device__ __forceinline__ float exact_dot(const float* __restrict__ xrow,
                                           const float* __restrict__ crow) {
    const float4* xp = (const float4*)xrow;
    const float4* cp = (const float4*)crow;
    float A = 0.f, B = 0.f;
    #pragma unroll 8
    for (int d4 = 0; d4 < 32; ++d4) {
        float4 xv = xp[d4], cv = cp[d4];
        A = __fmaf_rn(xv.x, cv.x, A);
        A = __fmaf_rn(xv.y, cv.y, A);
        A = __fmaf_rn(xv.z, cv.z, A);
        A = __fmaf_rn(xv.w, cv.w, A);
    }
    #pragma unroll 8
    for (int d4 = 32; d4 < 64; ++d4) {
        float4 xv = xp[d4], cv = cp[d4];
        B = __fmaf_rn(xv.x, cv.x, B);
        B = __fmaf_rn(xv.y, cv.y, B);
        B = __fmaf_rn(xv.z, cv.z, B);
        B = __fmaf_rn(xv.w, cv.w, B);
    }
    return __fadd_rn(A, B);
}

// --- csqr[k] (proven r2-r16, unchanged) ---
__global__ __launch_bounds__(256) void vq_csqr(const float* __restrict__ cb,
                                               float* __restrict__ csqr) {
    int gid  = blockIdx.x * 256 + threadIdx.x;
    int w    = gid >> 6;
    int lane = threadIdx.x & 63;
    if (w >= KCODES) return;
    float4 v = reinterpret_cast<const float4*>(cb)[w * (DDIM / 4) + lane];
    float s = v.x * v.x + v.y * v.y + v.z * v.z + v.w * v.w;
    #pragma unroll
    for (int off = 32; off > 0; off >>= 1) s += __shfl_down(s, off, 64);
    if (lane == 0) csqr[w] = s;
}

// --- xsqr[r] (proven r3-r16, unchanged) ---
__global__ __launch_bounds__(256) void vq_xsqr(const float* __restrict__ x,
                                               float* __restrict__ xsqr) {
    int w = threadIdx.x >> 6, lane = threadIdx.x & 63;
    int row = blockIdx.x * 4 + w;
    float4 v = reinterpret_cast<const float4*>(x + (size_t)row * DDIM)[lane];
    float s = v.x * v.x + v.y * v.y + v.z * v.z + v.w * v.w;
    #pragma unroll
    for (int off = 32; off > 0; off >>= 1) s += __shfl_down(s, off, 64);
    if (lane == 0) xsqr[row] = s;
}

// --- cb -> bf16 B-fragments (layout verified r4-r16): frag(nt,ks): lane l elem i =
//     cb[nt*16 + (l&15)][ks*32 + (l>>4)*8 + i]; linear id = (nt*8+ks)*64 + l ---
__global__ __launch_bounds__(256) void vq_cbfrag(const float* __restrict__ cb,
                                                 short* __restrict__ cbh) {
    int id   = blockIdx.x * 256 + threadIdx.x;
    int lane = id & 63;
    int ks   = (id >> 6) & 7;
    int nt   = id >> 9;
    int code = nt * 16 + (lane & 15);
    int d0   = ks * 32 + (lane >> 4) * 8;
    const float4* p = (const float4*)(cb + (size_t)code * DDIM + d0);
    float4 a = p[0], b = p[1];
    short8 v;
    v[0] = (short)f2bf(a.x); v[1] = (short)f2bf(a.y);
    v[2] = (short)f2bf(a.z); v[3] = (short)f2bf(a.w);
    v[4] = (short)f2bf(b.x); v[5] = (short)f2bf(b.y);
    v[6] = (short)f2bf(b.z); v[7] = (short)f2bf(b.w);
    *(short8*)(cbh + (size_t)id * 8) = v;
}

// --- main: 64 rows/block, 4 waves x 16 rows; r9 LDS staging; swapped-operand MFMA;
//     lane-local single-pass threshold; post-filtered exact rescore. ---
__global__ __launch_bounds__(256, 2) void vq_main(const float* __restrict__ x,
                                                  const float* __restrict__ cb,
                                                  const short* __restrict__ cbh,
                                                  const float* __restrict__ csqr,
                                                  const float* __restrict__ xsqr,
                                                  float* __restrict__ out) {
    __shared__ short              bstage[2][4 * 8 * 64 * 8];  // 2 x 32KB B chunks
    __shared__ float              csl[KCODES];                // 4KB
    __shared__ float              chk[16][16];                // self-check tile
    __shared__ unsigned long long keys[RPB];
    __shared__ unsigned           list[CAP];                  // 8KB, (q<<16)|(row<<10)|code
    __shared__ unsigned           qthrl[RPB];
    __shared__ int                fidx[RPB];
    __shared__ int                cnt, ovf;

    const int t    = threadIdx.x;
    const int lane = t & 63;
    const int w    = t >> 6;         // 0..3 (wave = 16-row tile)
    const int r0   = blockIdx.x * RPB;
    const int lr   = lane & 15;      // swapped layout: lane's X-ROW
    const int lg   = lane >> 4;      // lane's code sub-group

    ((float4*)csl)[t] = ((const float4*)csqr)[t];
    if (t < RPB) keys[t] = ~0ULL;
    if (t == 0) { cnt = 0; ovf = 0; }

    // A... x fragments (same registers as r4-r16; used as B-operand after the swap).
    short8 afr[8];
    {
        const float* xr = x + (size_t)(r0 + w * 16 + lr) * DDIM;
        #pragma unroll
        for (int ks = 0; ks < 8; ++ks) {
            float4 a = *(const float4*)&xr[ks * 32 + lg * 8];
            float4 b = *(const float4*)&xr[ks * 32 + lg * 8 + 4];
            short8 v;
            v[0] = (short)f2bf(a.x); v[1] = (short)f2bf(a.y);
            v[2] = (short)f2bf(a.z); v[3] = (short)f2bf(a.w);
            v[4] = (short)f2bf(b.x); v[5] = (short)f2bf(b.y);
            v[6] = (short)f2bf(b.z); v[7] = (short)f2bf(b.w);
            afr[ks] = v;
        }
    }

    const short8* cbh8 = (const short8*)cbh;   // fragment-linear, 16B units

    // r9-proven staging pipeline: pf holds chunk (c+1) while computing chunk c.
    short8 pf[8];
    #pragma unroll
    for (int i = 0; i < 8; ++i) pf[i] = cbh8[(size_t)0 * 2048 + i * 256 + t];
    {
        short8* dst = (short8*)bstage[0];
        #pragma unroll
        for (int i = 0; i < 8; ++i) dst[i * 256 + t] = pf[i];
        #pragma unroll
        for (int i = 0; i < 8; ++i) pf[i] = cbh8[(size_t)1 * 2048 + i * 256 + t];
    }
    __syncthreads();

    float runm = __builtin_inff();

    // ---- priming: chunk-0 tiles min-only (cuts appends H(256)->~ln16) ----
    {
        const short* bs = bstage[0];
        #pragma unroll
        for (int m = 0; m < 4; ++m) {
            short8 bv[8];
            #pragma unroll
            for (int ks = 0; ks < 8; ++ks)
                bv[ks] = *(const short8*)&bs[((m * 8 + ks) * 64 + lane) * 8];
            f32x4 af = (f32x4){0.f, 0.f, 0.f, 0.f};
            #pragma unroll
            for (int ks = 0; ks < 8; ++ks)
                af = __builtin_amdgcn_mfma_f32_16x16x32_bf16(bv[ks], afr[ks], af, 0, 0, 0);  // SWAPPED
            float4 cs4 = *(const float4*)&csl[m * 16 + lg * 4];
            runm = fminf(runm, __fmaf_rn(-2.f, af[0], __fadd_rn(cs4.x, 1.0f)));
            runm = fminf(runm, __fmaf_rn(-2.f, af[1], __fadd_rn(cs4.y, 1.0f)));
            runm = fminf(runm, __fmaf_rn(-2.f, af[2], __fadd_rn(cs4.z, 1.0f)));
            runm = fminf(runm, __fmaf_rn(-2.f, af[3], __fadd_rn(cs4.w, 1.0f)));
        }
    }

    // ---- single pass, zero shuffles in the epilogue ----
    for (int c = 0; c < NCHUNK; ++c) {
        if (c + 1 < NCHUNK) {
            short8* dst = (short8*)bstage[(c + 1) & 1];
            #pragma unroll
            for (int i = 0; i < 8; ++i) dst[i * 256 + t] = pf[i];
        }
        if (c + 2 < NCHUNK) {
            const size_t cb2 = (size_t)(c + 2) * 2048;
            #pragma unroll
            for (int i = 0; i < 8; ++i) pf[i] = cbh8[cb2 + i * 256 + t];
        }
        const short* bs = bstage[c & 1];
        #pragma unroll
        for (int m = 0; m < 4; ++m) {
            const int nt = c * 4 + m;
            short8 bv[8];
            #pragma unroll
            for (int ks = 0; ks < 8; ++ks)
                bv[ks] = *(const short8*)&bs[((m * 8 + ks) * 64 + lane) * 8];
            f32x4 af = (f32x4){0.f, 0.f, 0.f, 0.f};
            #pragma unroll
            for (int ks = 0; ks < 8; ++ks)
                af = __builtin_amdgcn_mfma_f32_16x16x32_bf16(bv[ks], afr[ks], af, 0, 0, 0);  // SWAPPED

            float4 cs4 = *(const float4*)&csl[nt * 16 + lg * 4];
            float s[4];
            s[0] = __fmaf_rn(-2.f, af[0], __fadd_rn(cs4.x, 1.0f));
            s[1] = __fmaf_rn(-2.f, af[1], __fadd_rn(cs4.y, 1.0f));
            s[2] = __fmaf_rn(-2.f, af[2], __fadd_rn(cs4.z, 1.0f));
            s[3] = __fmaf_rn(-2.f, af[3], __fadd_rn(cs4.w, 1.0f));
            runm = fminf(runm, fminf(fminf(s[0], s[1]), fminf(s[2], s[3])));
            if (w == 0 && nt == 0) {                      // self-check store (wave-uniform guard)
                #pragma unroll
                for (int j = 0; j < 4; ++j) chk[lr][lg * 4 + j] = s[j];
            }
            const int row = w * 16 + lr;
            #pragma unroll
            for (int j = 0; j < 4; ++j) {
                if (s[j] <= runm + MARGIN) {              // lane-local threshold (sound)
                    int code = nt * 16 + lg * 4 + j;
                    int pos = atomicAdd(&cnt, 1);
                    if (pos < CAP) list[pos] = (qscore(s[j]) << 16) | ((unsigned)row << 10) | (unsigned)code;
                    else ovf = 1;
                }
            }
        }
        __syncthreads();   // chunk c+1 visible; buf[c&1] readers done
    }

    // final row min: combine the 4 lanes {lr, lr+16, lr+32, lr+48} — 2 shfls ONCE
    {
        float v = runm;
        v = fminf(v, __shfl_xor(v, 16, 64));
        v = fminf(v, __shfl_xor(v, 32, 64));
        if (lane < 16) qthrl[w * 16 + lane] = qscore(v + MARGIN);
    }
    __syncthreads();

    // ---- 16-point orientation self-check (insurance; ~0.4us) ----
    if (t < 16) {
        int code = (t * 5) & 15;
        float dot = exact_dot(x + (size_t)(r0 + t) * DDIM, cb + (size_t)code * DDIM);
        float ex  = __fmaf_rn(-2.f, dot, __fadd_rn(csl[code], 1.0f));
        if (fabsf(ex - chk[t][code]) > CHKTHR) ovf = 1;
    }
    __syncthreads();

    // ---- post-filter + exact rescore (r2-proven chain + grid formula) ----
    if (ovf || cnt > CAP) {
        for (int it = t; it < RPB * KCODES; it += 256) {   // safety net
            int row = it >> 10, code = it & (KCODES - 1);
            float dot = exact_dot(x + (size_t)(r0 + row) * DDIM, cb + (size_t)code * DDIM);
            float s   = __fmaf_rn(-2.f, dot, __fadd_rn(csl[code], xsqr[r0 + row]));
            atomicMin(&keys[row], ((unsigned long long)__float_as_uint(s) << 32) | (unsigned)code);
        }
    } else {
        for (int i = t; i < cnt; i += 256) {
            unsigned e = list[i];
            int row    = (int)((e >> 10) & 63u);
            if ((e >> 16) > qthrl[row]) continue;          // conservative final filter
            int code   = (int)(e & 0x3FFu);
            float dot = exact_dot(x + (size_t)(r0 + row) * DDIM, cb + (size_t)code * DDIM);
            float s   = __fmaf_rn(-2.f, dot, __fadd_rn(csl[code], xsqr[r0 + row]));
            atomicMin(&keys[row], ((unsigned long long)__float_as_uint(s) << 32) | (unsigned)code);
        }
    }
    __syncthreads();

    if (t < RPB) {
        int code = (int)(unsigned)(keys[t] & 0xffffffffu);
        fidx[t] = code;
        out[(size_t)2 * NROWS * DDIM + (r0 + t)] = (float)code;
    }
    __syncthreads();

    // gather winning codes: 64 rows x 64 float4, coalesced
    const float4* cb4  = (const float4*)cb;
    float4*       out0 = (float4*)out;
    float4*       out1 = out0 + (size_t)NROWS * (DDIM / 4);
    #pragma unroll
    for (int i = 0; i < 16; ++i) {
        int it  = i * 256 + t;
        int row = it >> 6, col = it & 63;
        float4 v = cb4[(size_t)fidx[row] * (DDIM / 4) + col];
        size_t o = (size_t)(r0 + row) * (DDIM / 4) + col;
        out0[o] = v;
        out1[o] = v;
    }
}

extern "C" void kernel_launch(void* const* d_in, const int* in_sizes, int n_in,
                              void* d_out, int out_size, void* d_ws, size_t ws_size,
                              hipStream_t stream) {
    const float* x   = (const float*)d_in[0];   // z_e_x   [32768,256]
    const float* cb  = (const float*)d_in[1];   // codebook [1024,256]
    float*       out = (float*)d_out;

    float* ws_csqr = (float*)d_ws;                // [1024]
    float* ws_xsqr = ws_csqr + KCODES;            // [32768]
    short* ws_cbh  = (short*)(ws_xsqr + NROWS);   // [1024*256] bf16 frags

    vq_cbfrag<<<128,        256, 0, stream>>>(cb, ws_cbh);
    vq_csqr  <<<256,        256, 0, stream>>>(cb, ws_csqr);
    vq_xsqr  <<<NROWS / 4,  256, 0, stream>>>(x, ws_xsqr);
    vq_main  <<<NROWS / RPB, 256, 0, stream>>>(x, cb, ws_cbh, ws_csqr, ws_xsqr, out);
}

// Round 18
// 111.522 us; speedup vs baseline: 1.2204x; 1.0791x over previous
//
#include <hip/hip_runtime.h>

// VQEmbedding: B=32,T=1024,D=256,K=1024. N=32768 rows.
// Exact score (proven r2-r17): s = fl32( fl32(csqr_k + xsqr_i) - 2*dot_ik ), argmin,
// first-index ties via packed u64 keys. bf16 MFMA approx; exact fp32 rescore (r2 chain).
// SWAPPED MFMA orientation (mfma(bv,afr): lane lr = row, lg*4+j = code) CONFIRMED r17.
// r18 change (r9-r17 invariant: ALL variants idle 70-80% at Occupancy=20% — 2 blocks/CU
// cannot hide barrier-drain; independent blocks are the only barrier overlap):
//  - chunk 32KB -> 16KB (2 nt, dbuf 32KB); LDS total ~39.2KB -> 4 blocks/CU (16 waves).
//  - staging via global_load_lds (r10-proven; no pf registers); live ~93 VGPR fits
//    the 128 cap of launch_bounds(256,4) (r13's crush was a >128 live set; ours isn't).
//  - r9's proven two-pass epilogue discipline: pass1 branch-free lane-local min only;
//    ONE 2-shfl row combine at boundary; pass2 appends vs tight FINAL threshold
//    (~83/block) — avoids r16/r17's in-loop append cost (LDS-atomic latency).

#define NROWS  32768
#define DDIM   256
#define KCODES 1024
#define MARGIN 1.5e-3f
#define CHKTHR 2.5e-3f
#define CAP    256
#define RPB    64          // rows per block (4 waves x 16 rows)
#define NCHUNK 32          // chunk = 2 nt = 32 codes = 16KB frags

typedef __attribute__((ext_vector_type(8))) short short8;
typedef __attribute__((ext_vector_type(4))) float f32x4;

__device__ __forceinline__ unsigned short f2bf(float f) {   // RNE f32->bf16
    unsigned u = __float_as_uint(f);
    return (unsigned short)((u + 0x7FFFu + ((u >> 16) & 1u)) >> 16);
}

// exact fp32 dot — BIT-IDENTICAL chain to r2-r17 (proven). DO NOT reorder.
__device__ __forceinline__ float exact_dot(const float* __restrict__ xrow,
                                           const float* __restrict__ crow) {
    const float4* xp = (const float4*)xrow;
    const float4* cp = (const float4*)crow;
    float A = 0.f, B = 0.f;
    #pragma unroll 8
    for (int d4 = 0; d4 < 32; ++d4) {
        float4 xv = xp[d4], cv = cp[d4];
        A = __fmaf_rn(xv.x, cv.x, A);
        A = __fmaf_rn(xv.y, cv.y, A);
        A = __fmaf_rn(xv.z, cv.z, A);
        A = __fmaf_rn(xv.w, cv.w, A);
    }
    #pragma unroll 8
    for (int d4 = 32; d4 < 64; ++d4) {
        float4 xv = xp[d4], cv = cp[d4];
        B = __fmaf_rn(xv.x, cv.x, B);
        B = __fmaf_rn(xv.y, cv.y, B);
        B = __fmaf_rn(xv.z, cv.z, B);
        B = __fmaf_rn(xv.w, cv.w, B);
    }
    return __fadd_rn(A, B);
}

// --- csqr[k] (proven r2-r17, unchanged) ---
__global__ __launch_bounds__(256) void vq_csqr(const float* __restrict__ cb,
                                               float* __restrict__ csqr) {
    int gid  = blockIdx.x * 256 + threadIdx.x;
    int w    = gid >> 6;
    int lane = threadIdx.x & 63;
    if (w >= KCODES) return;
    float4 v = reinterpret_cast<const float4*>(cb)[w * (DDIM / 4) + lane];
    float s = v.x * v.x + v.y * v.y + v.z * v.z + v.w * v.w;
    #pragma unroll
    for (int off = 32; off > 0; off >>= 1) s += __shfl_down(s, off, 64);
    if (lane == 0) csqr[w] = s;
}

// --- xsqr[r] (proven r3-r17, unchanged) ---
__global__ __launch_bounds__(256) void vq_xsqr(const float* __restrict__ x,
                                               float* __restrict__ xsqr) {
    int w = threadIdx.x >> 6, lane = threadIdx.x & 63;
    int row = blockIdx.x * 4 + w;
    float4 v = reinterpret_cast<const float4*>(x + (size_t)row * DDIM)[lane];
    float s = v.x * v.x + v.y * v.y + v.z * v.z + v.w * v.w;
    #pragma unroll
    for (int off = 32; off > 0; off >>= 1) s += __shfl_down(s, off, 64);
    if (lane == 0) xsqr[row] = s;
}

// --- cb -> bf16 B-fragments (layout verified r4-r17): frag(nt,ks): lane l elem i =
//     cb[nt*16 + (l&15)][ks*32 + (l>>4)*8 + i]; linear id = (nt*8+ks)*64 + l ---
__global__ __launch_bounds__(256) void vq_cbfrag(const float* __restrict__ cb,
                                                 short* __restrict__ cbh) {
    int id   = blockIdx.x * 256 + threadIdx.x;
    int lane = id & 63;
    int ks   = (id >> 6) & 7;
    int nt   = id >> 9;
    int code = nt * 16 + (lane & 15);
    int d0   = ks * 32 + (lane >> 4) * 8;
    const float4* p = (const float4*)(cb + (size_t)code * DDIM + d0);
    float4 a = p[0], b = p[1];
    short8 v;
    v[0] = (short)f2bf(a.x); v[1] = (short)f2bf(a.y);
    v[2] = (short)f2bf(a.z); v[3] = (short)f2bf(a.w);
    v[4] = (short)f2bf(b.x); v[5] = (short)f2bf(b.y);
    v[6] = (short)f2bf(b.z); v[7] = (short)f2bf(b.w);
    *(short8*)(cbh + (size_t)id * 8) = v;
}

// --- main: 64 rows/block, 4 waves x 16 rows; 16KB chunks dbuf'd via global_load_lds;
//     swapped MFMA; two-pass (min-only, then tight-threshold append); exact rescore ---
__global__ __launch_bounds__(256, 4) void vq_main(const float* __restrict__ x,
                                                  const float* __restrict__ cb,
                                                  const short* __restrict__ cbh,
                                                  const float* __restrict__ csqr,
                                                  const float* __restrict__ xsqr,
                                                  float* __restrict__ out) {
    __shared__ short              bstage[2][2 * 8 * 64 * 8];  // 2 x 16KB B chunks
    __shared__ float              csl[KCODES];                // 4KB
    __shared__ float              chk[8][16];                 // orientation self-check
    __shared__ unsigned long long keys[RPB];
    __shared__ unsigned           list[CAP];                  // 1KB
    __shared__ int                fidx[RPB];
    __shared__ int                cnt, ovf;

    const int t    = threadIdx.x;
    const int lane = t & 63;
    const int w    = t >> 6;         // 0..3 (wave = 16-row tile)
    const int r0   = blockIdx.x * RPB;
    const int lr   = lane & 15;      // swapped layout: lane's ROW
    const int lg   = lane >> 4;      // lane's code sub-group

    ((float4*)csl)[t] = ((const float4*)csqr)[t];
    if (t < RPB) keys[t] = ~0ULL;
    if (t == 0) { cnt = 0; ovf = 0; }

    // x fragments (same mapping as r4-r17; B-operand after the swap).
    short8 afr[8];
    {
        const float* xr = x + (size_t)(r0 + w * 16 + lr) * DDIM;
        #pragma unroll
        for (int ks = 0; ks < 8; ++ks) {
            float4 a = *(const float4*)&xr[ks * 32 + lg * 8];
            float4 b = *(const float4*)&xr[ks * 32 + lg * 8 + 4];
            short8 v;
            v[0] = (short)f2bf(a.x); v[1] = (short)f2bf(a.y);
            v[2] = (short)f2bf(a.z); v[3] = (short)f2bf(a.w);
            v[4] = (short)f2bf(b.x); v[5] = (short)f2bf(b.y);
            v[6] = (short)f2bf(b.z); v[7] = (short)f2bf(b.w);
            afr[ks] = v;
        }
    }

    // DMA staging (r10-proven): wave-uniform LDS dst, per-lane global src.
    auto stage_chunk = [&](int buf, int c) {
        #pragma unroll
        for (int i = 0; i < 4; ++i) {
            const int off = (i * 4 + w) * 1024;
            const char* src = (const char*)cbh + (size_t)c * 16384 + off + lane * 16;
            __builtin_amdgcn_global_load_lds(
                (const __attribute__((address_space(1))) void*)src,
                (__attribute__((address_space(3))) void*)((char*)bstage[buf] + off),
                16, 0, 0);
        }
    };

    stage_chunk(0, 0);
    __syncthreads();   // vmcnt drained before barrier -> chunk 0 ready

    float runm = __builtin_inff();
    float thr  = 0.f;

    for (int cc = 0; cc < 2 * NCHUNK; ++cc) {
        const int c = cc & (NCHUNK - 1);
        if (cc + 1 < 2 * NCHUNK) stage_chunk((cc + 1) & 1, (cc + 1) & (NCHUNK - 1));

        const short* bs = bstage[cc & 1];
        #pragma unroll
        for (int m = 0; m < 2; ++m) {
            const int nt = c * 2 + m;
            short8 bv[8];
            #pragma unroll
            for (int ks = 0; ks < 8; ++ks)
                bv[ks] = *(const short8*)&bs[((m * 8 + ks) * 64 + lane) * 8];
            f32x4 af = (f32x4){0.f, 0.f, 0.f, 0.f};
            #pragma unroll
            for (int ks = 0; ks < 8; ++ks)
                af = __builtin_amdgcn_mfma_f32_16x16x32_bf16(bv[ks], afr[ks], af, 0, 0, 0);  // SWAPPED (r17-confirmed)

            float4 cs4 = *(const float4*)&csl[nt * 16 + lg * 4];
            float s0 = __fmaf_rn(-2.f, af[0], __fadd_rn(cs4.x, 1.0f));
            float s1 = __fmaf_rn(-2.f, af[1], __fadd_rn(cs4.y, 1.0f));
            float s2 = __fmaf_rn(-2.f, af[2], __fadd_rn(cs4.z, 1.0f));
            float s3 = __fmaf_rn(-2.f, af[3], __fadd_rn(cs4.w, 1.0f));

            if (cc < NCHUNK) {
                // pass 1: branch-free lane-local running min (r9-cheap epilogue)
                runm = fminf(runm, fminf(fminf(s0, s1), fminf(s2, s3)));
                if (w == 0 && nt == 0 && lr < 8) {        // self-check tile (rows 0..7)
                    chk[lr][lg * 4 + 0] = s0;
                    chk[lr][lg * 4 + 1] = s1;
                    chk[lr][lg * 4 + 2] = s2;
                    chk[lr][lg * 4 + 3] = s3;
                }
            } else {
                // pass 2: bit-identical recompute, append vs tight FINAL threshold
                const int row = w * 16 + lr;
                float s[4] = {s0, s1, s2, s3};
                #pragma unroll
                for (int j = 0; j < 4; ++j) {
                    if (s[j] <= thr) {
                        int code = nt * 16 + lg * 4 + j;
                        int pos = atomicAdd(&cnt, 1);
                        if (pos < CAP) list[pos] = ((unsigned)row << 10) | (unsigned)code;
                        else ovf = 1;
                    }
                }
            }
        }
        // pass boundary: combine lanes {lr, lr+16, lr+32, lr+48} -> final row min
        if (cc == NCHUNK - 1) {
            float v = runm;
            v = fminf(v, __shfl_xor(v, 16, 64));
            v = fminf(v, __shfl_xor(v, 32, 64));
            thr = v + MARGIN;                             // lane-local, row-exact
        }
        __syncthreads();   // staged chunk visible; buf readers done
    }

    // ---- orientation self-check (insurance): 8 rows x 16 codes exact vs chk ----
    if (t < 128) {
        int row = t >> 4, code = t & 15;
        float dot = exact_dot(x + (size_t)(r0 + row) * DDIM, cb + (size_t)code * DDIM);
        float ex  = __fmaf_rn(-2.f, dot, __fadd_rn(csl[code], 1.0f));
        if (fabsf(ex - chk[row][code]) > CHKTHR) ovf = 1;
    }
    __syncthreads();

    // ---- exact rescore (r2-proven chain + grid formula), u64 first-index argmin ----
    if (ovf || cnt > CAP) {
        for (int it = t; it < RPB * KCODES; it += 256) {   // safety net
            int row = it >> 10, code = it & (KCODES - 1);
            float dot = exact_dot(x + (size_t)(r0 + row) * DDIM, cb + (size_t)code * DDIM);
            float s   = __fmaf_rn(-2.f, dot, __fadd_rn(csl[code], xsqr[r0 + row]));
            atomicMin(&keys[row], ((unsigned long long)__float_as_uint(s) << 32) | (unsigned)code);
        }
    } else {
        for (int i = t; i < cnt; i += 256) {
            unsigned e = list[i];
            int row = (int)(e >> 10), code = (int)(e & 0x3FFu);
            float dot = exact_dot(x + (size_t)(r0 + row) * DDIM, cb + (size_t)code * DDIM);
            float s   = __fmaf_rn(-2.f, dot, __fadd_rn(csl[code], xsqr[r0 + row]));
            atomicMin(&keys[row], ((unsigned long long)__float_as_uint(s) << 32) | (unsigned)code);
        }
    }
    __syncthreads();

    if (t < RPB) {
        int code = (int)(unsigned)(keys[t] & 0xffffffffu);
        fidx[t] = code;
        out[(size_t)2 * NROWS * DDIM + (r0 + t)] = (float)code;
    }
    __syncthreads();

    // gather winning codes: 64 rows x 64 float4, coalesced
    const float4* cb4  = (const float4*)cb;
    float4*       out0 = (float4*)out;
    float4*       out1 = out0 + (size_t)NROWS * (DDIM / 4);
    #pragma unroll
    for (int i = 0; i < 16; ++i) {
        int it  = i * 256 + t;
        int row = it >> 6, col = it & 63;
        float4 v = cb4[(size_t)fidx[row] * (DDIM / 4) + col];
        size_t o = (size_t)(r0 + row) * (DDIM / 4) + col;
        out0[o] = v;
        out1[o] = v;
    }
}

extern "C" void kernel_launch(void* const* d_in, const int* in_sizes, int n_in,
                              void* d_out, int out_size, void* d_ws, size_t ws_size,
                              hipStream_t stream) {
    const float* x   = (const float*)d_in[0];   // z_e_x   [32768,256]
    const float* cb  = (const float*)d_in[1];   // codebook [1024,256]
    float*       out = (float*)d_out;

    float* ws_csqr = (float*)d_ws;                // [1024]
    float* ws_xsqr = ws_csqr + KCODES;            // [32768]
    short* ws_cbh  = (short*)(ws_xsqr + NROWS);   // [1024*256] bf16 frags

    vq_cbfrag<<<128,        256, 0, stream>>>(cb, ws_cbh);
    vq_csqr  <<<256,        256, 0, stream>>>(cb, ws_csqr);
    vq_xsqr  <<<NROWS / 4,  256, 0, stream>>>(x, ws_xsqr);
    vq_main  <<<NROWS / RPB, 256, 0, stream>>>(x, cb, ws_cbh, ws_csqr, ws_xsqr, out);
}